// Round 1
// baseline (1695.273 us; speedup 1.0000x reference)
//
#include <hip/hip_runtime.h>
#include <hip/hip_bf16.h>
#include <stdint.h>

#define Dm 1024
#define Rr 32
#define MT 32768
#define NLAYER 6

typedef __attribute__((ext_vector_type(8))) short bfvec8;
typedef __attribute__((ext_vector_type(4))) float fvec4;

__device__ __forceinline__ float bf2f(unsigned short u){
    union { unsigned int i; float f; } v; v.i = ((unsigned int)u) << 16; return v.f;
}
__device__ __forceinline__ unsigned short f2bf(float f){
    union { float f; unsigned int i; } v; v.f = f;
    unsigned int x = v.i;
    return (unsigned short)((x + 0x7fffu + ((x >> 16) & 1u)) >> 16);
}

__device__ __forceinline__ void gload_lds16(const void* g, void* lds){
    __builtin_amdgcn_global_load_lds(
        (const __attribute__((address_space(1))) void*)(uintptr_t)g,
        (__attribute__((address_space(3))) void*)(unsigned int)(uintptr_t)lds,
        16, 0, 0);
}

// ---- dequant 4-bit codes -> bf16 weights: w = (q/7.5 - 1) * scale[o][i/16]
__global__ __launch_bounds__(256) void prep_weights(const int* __restrict__ q,
                                                    const float* __restrict__ sc,
                                                    unsigned short* __restrict__ wbf){
    int idx = blockIdx.x * 256 + threadIdx.x;          // over 6*1024*1024
    int col  = idx & (Dm - 1);
    int rowl = idx >> 10;                               // l*1024 + o
    float s = sc[rowl * (Dm / 16) + (col >> 4)];
    float w = ((float)q[idx] * (1.0f / 7.5f) - 1.0f) * s;
    wbf[idx] = f2bf(w);
}

// ---- fp32 -> bf16 convert (n multiple of 1024)
__global__ __launch_bounds__(256) void conv_bf16_kernel(const float* __restrict__ in,
                                                        unsigned short* __restrict__ out){
    size_t i = ((size_t)blockIdx.x * 256 + threadIdx.x) * 4;
    float4 v = *(const float4*)(in + i);
    ushort4 o;
    o.x = f2bf(v.x); o.y = f2bf(v.y); o.z = f2bf(v.z); o.w = f2bf(v.w);
    *(ushort4*)(out + i) = o;
}

// ---- t = A[M,1024] @ la^T[1024,32] -> bf16 [M,32]; one block = 128 rows, wave = 32 rows
__global__ __launch_bounds__(256) void lora_t_kernel(const unsigned short* __restrict__ A,
                                                     const unsigned short* __restrict__ la,
                                                     unsigned short* __restrict__ T){
    const int wave = threadIdx.x >> 6, lane = threadIdx.x & 63;
    const int quad = lane >> 4, l16 = lane & 15;
    const int row_base = blockIdx.x * 128 + wave * 32;
    fvec4 acc[2][2] = {};
    for (int k = 0; k < Dm; k += 32) {
        bfvec8 a0 = *(const bfvec8*)(A + (size_t)(row_base + l16) * Dm + k + quad * 8);
        bfvec8 a1 = *(const bfvec8*)(A + (size_t)(row_base + 16 + l16) * Dm + k + quad * 8);
        bfvec8 b0 = *(const bfvec8*)(la + (size_t)(l16) * Dm + k + quad * 8);
        bfvec8 b1 = *(const bfvec8*)(la + (size_t)(16 + l16) * Dm + k + quad * 8);
        acc[0][0] = __builtin_amdgcn_mfma_f32_16x16x32_bf16(a0, b0, acc[0][0], 0, 0, 0);
        acc[0][1] = __builtin_amdgcn_mfma_f32_16x16x32_bf16(a0, b1, acc[0][1], 0, 0, 0);
        acc[1][0] = __builtin_amdgcn_mfma_f32_16x16x32_bf16(a1, b0, acc[1][0], 0, 0, 0);
        acc[1][1] = __builtin_amdgcn_mfma_f32_16x16x32_bf16(a1, b1, acc[1][1], 0, 0, 0);
    }
    #pragma unroll
    for (int mi = 0; mi < 2; mi++)
        #pragma unroll
        for (int ni = 0; ni < 2; ni++)
            #pragma unroll
            for (int r = 0; r < 4; r++) {
                int row = row_base + mi * 16 + quad * 4 + r;
                int col = ni * 16 + l16;
                T[(size_t)row * Rr + col] = f2bf(acc[mi][ni][r]);
            }
}

// ---- main GEMM: C[m,n] = sum_k A[m,k]*W[n,k] + sum_r T[m,r]*LB[n,r] + bias[n] (+resid)
// 128x128 tile, BK=64, 4 waves each 64x64 (4x4 of 16x16x32 bf16 MFMA)
__global__ __launch_bounds__(256) void qlora_gemm(
    const unsigned short* __restrict__ A,
    const unsigned short* __restrict__ W,
    const unsigned short* __restrict__ T,
    const unsigned short* __restrict__ LB,
    const float* __restrict__ bias,
    const float* __restrict__ resid,
    float* __restrict__ outf,
    unsigned short* __restrict__ outb)
{
    __shared__ unsigned short As[128 * 64];
    __shared__ unsigned short Ws[128 * 64];
    const int tid = threadIdx.x;
    const int wave = tid >> 6, lane = tid & 63;
    const int quad = lane >> 4, l16 = lane & 15;
    const int wm = wave >> 1, wn = wave & 1;
    const int m0 = blockIdx.y * 128, n0 = blockIdx.x * 128;
    const int r8 = tid >> 3;            // 0..31: row within pass
    const int o8 = (tid & 7) * 8;       // element offset within row

    fvec4 acc[4][4] = {};

    for (int k0 = 0; k0 < Dm; k0 += 64) {
        #pragma unroll
        for (int p = 0; p < 4; p++) {
            int row = p * 32 + r8;
            gload_lds16(A + (size_t)(m0 + row) * Dm + k0 + o8,
                        (char*)As + (p * 256 + wave * 64) * 16);
            gload_lds16(W + (size_t)(n0 + row) * Dm + k0 + o8,
                        (char*)Ws + (p * 256 + wave * 64) * 16);
        }
        __syncthreads();
        #pragma unroll
        for (int ks = 0; ks < 64; ks += 32) {
            bfvec8 af[4], bw[4];
            #pragma unroll
            for (int i = 0; i < 4; i++) {
                af[i] = *(const bfvec8*)(As + (wm * 64 + i * 16 + l16) * 64 + ks + quad * 8);
                bw[i] = *(const bfvec8*)(Ws + (wn * 64 + i * 16 + l16) * 64 + ks + quad * 8);
            }
            #pragma unroll
            for (int mi = 0; mi < 4; mi++)
                #pragma unroll
                for (int ni = 0; ni < 4; ni++)
                    acc[mi][ni] = __builtin_amdgcn_mfma_f32_16x16x32_bf16(af[mi], bw[ni], acc[mi][ni], 0, 0, 0);
        }
        __syncthreads();
    }

    // LoRA tail: one K=32 step with T (A-operand) and LB (B-operand), direct global reads
    {
        bfvec8 tf[4], lf[4];
        #pragma unroll
        for (int i = 0; i < 4; i++) {
            tf[i] = *(const bfvec8*)(T + (size_t)(m0 + wm * 64 + i * 16 + l16) * Rr + quad * 8);
            lf[i] = *(const bfvec8*)(LB + (size_t)(n0 + wn * 64 + i * 16 + l16) * Rr + quad * 8);
        }
        #pragma unroll
        for (int mi = 0; mi < 4; mi++)
            #pragma unroll
            for (int ni = 0; ni < 4; ni++)
                acc[mi][ni] = __builtin_amdgcn_mfma_f32_16x16x32_bf16(tf[mi], lf[ni], acc[mi][ni], 0, 0, 0);
    }

    #pragma unroll
    for (int ni = 0; ni < 4; ni++) {
        const int col = n0 + wn * 64 + ni * 16 + l16;
        const float bv = bias[col];
        #pragma unroll
        for (int mi = 0; mi < 4; mi++) {
            const int rowb = m0 + wm * 64 + mi * 16 + quad * 4;
            #pragma unroll
            for (int r = 0; r < 4; r++) {
                float v = acc[mi][ni][r] + bv;
                size_t off = (size_t)(rowb + r) * Dm + col;
                if (resid) v += resid[off];
                if (outf) outf[off] = v;
                if (outb) outb[off] = f2bf(v);
            }
        }
    }
}

// ---- LayerNorm + exact GELU over rows of 1024, one block per row
__global__ __launch_bounds__(256) void ln_gelu_kernel(const unsigned short* __restrict__ Y,
                                                      const float* __restrict__ g,
                                                      const float* __restrict__ b,
                                                      unsigned short* __restrict__ Aout){
    const int row = blockIdx.x;
    const int tid = threadIdx.x;
    const unsigned short* yr = Y + (size_t)row * Dm;
    ushort4 u = *(const ushort4*)(yr + tid * 4);
    float x0 = bf2f(u.x), x1 = bf2f(u.y), x2 = bf2f(u.z), x3 = bf2f(u.w);
    float s  = x0 + x1 + x2 + x3;
    float ss = x0 * x0 + x1 * x1 + x2 * x2 + x3 * x3;
    #pragma unroll
    for (int d = 32; d > 0; d >>= 1) {
        s  += __shfl_down(s, d);
        ss += __shfl_down(ss, d);
    }
    __shared__ float sb[8];
    const int wave = tid >> 6, lane = tid & 63;
    if (lane == 0) { sb[wave] = s; sb[4 + wave] = ss; }
    __syncthreads();
    s  = sb[0] + sb[1] + sb[2] + sb[3];
    ss = sb[4] + sb[5] + sb[6] + sb[7];
    const float mu = s * (1.0f / Dm);
    const float var = ss * (1.0f / Dm) - mu * mu;
    const float rstd = rsqrtf(var + 1e-5f);
    float4 gv = *(const float4*)(g + tid * 4);
    float4 bv = *(const float4*)(b + tid * 4);
    float z0 = (x0 - mu) * rstd * gv.x + bv.x;
    float z1 = (x1 - mu) * rstd * gv.y + bv.y;
    float z2 = (x2 - mu) * rstd * gv.z + bv.z;
    float z3 = (x3 - mu) * rstd * gv.w + bv.w;
    const float k = 0.70710678118654752f;
    float a0 = 0.5f * z0 * (1.0f + erff(z0 * k));
    float a1 = 0.5f * z1 * (1.0f + erff(z1 * k));
    float a2 = 0.5f * z2 * (1.0f + erff(z2 * k));
    float a3 = 0.5f * z3 * (1.0f + erff(z3 * k));
    ushort4 o;
    o.x = f2bf(a0); o.y = f2bf(a1); o.z = f2bf(a2); o.w = f2bf(a3);
    *(ushort4*)(Aout + (size_t)row * Dm + tid * 4) = o;
}

extern "C" void kernel_launch(void* const* d_in, const int* in_sizes, int n_in,
                              void* d_out, int out_size, void* d_ws, size_t ws_size,
                              hipStream_t stream) {
    (void)in_sizes; (void)n_in; (void)out_size; (void)ws_size;
    const float* x   = (const float*)d_in[0];
    const int*   qw  = (const int*)d_in[1];
    const float* sc  = (const float*)d_in[2];
    const float* bia = (const float*)d_in[3];
    const float* la  = (const float*)d_in[4];
    const float* lb  = (const float*)d_in[5];
    const float* gam = (const float*)d_in[6];
    const float* bet = (const float*)d_in[7];
    float* out = (float*)d_out;

    char* p = (char*)d_ws;
    unsigned short* Wbf  = (unsigned short*)p; p += (size_t)NLAYER * Dm * Dm * 2;
    unsigned short* labf = (unsigned short*)p; p += (size_t)NLAYER * Rr * Dm * 2;
    unsigned short* lbbf = (unsigned short*)p; p += (size_t)NLAYER * Dm * Rr * 2;
    unsigned short* Tbuf = (unsigned short*)p; p += (size_t)MT * Rr * 2;
    unsigned short* Pb   = (unsigned short*)p; p += (size_t)MT * Dm * 2;
    unsigned short* Qb   = (unsigned short*)p; p += (size_t)MT * Dm * 2;

    prep_weights<<<NLAYER * Dm * Dm / 256, 256, 0, stream>>>(qw, sc, Wbf);
    conv_bf16_kernel<<<NLAYER * Rr * Dm / 4 / 256, 256, 0, stream>>>(la, labf);
    conv_bf16_kernel<<<NLAYER * Dm * Rr / 4 / 256, 256, 0, stream>>>(lb, lbbf);
    conv_bf16_kernel<<<MT * (Dm / 4) / 256, 256, 0, stream>>>(x, Pb);

    unsigned short *curP = Pb, *curQ = Qb;
    for (int blk = 0; blk < 3; blk++) {
        int i0 = 2 * blk, i1 = i0 + 1;
        lora_t_kernel<<<MT / 128, 256, 0, stream>>>(curP, labf + (size_t)i0 * Rr * Dm, Tbuf);
        qlora_gemm<<<dim3(8, MT / 128), 256, 0, stream>>>(
            curP, Wbf + (size_t)i0 * Dm * Dm, Tbuf, lbbf + (size_t)i0 * Dm * Rr,
            bia + i0 * Dm, nullptr, nullptr, curQ);
        ln_gelu_kernel<<<MT, 256, 0, stream>>>(curQ, gam + blk * Dm, bet + blk * Dm, curP);
        lora_t_kernel<<<MT / 128, 256, 0, stream>>>(curP, labf + (size_t)i1 * Rr * Dm, Tbuf);
        qlora_gemm<<<dim3(8, MT / 128), 256, 0, stream>>>(
            curP, Wbf + (size_t)i1 * Dm * Dm, Tbuf, lbbf + (size_t)i1 * Dm * Rr,
            bia + i1 * Dm, blk == 0 ? x : (const float*)out, out, curQ);
        unsigned short* t = curP; curP = curQ; curQ = t;
    }
}

// Round 2
// 1585.306 us; speedup vs baseline: 1.0694x; 1.0694x over previous
//
#include <hip/hip_runtime.h>
#include <hip/hip_bf16.h>
#include <stdint.h>

#define Dm 1024
#define Rr 32
#define MT 32768
#define NLAYER 6

typedef __attribute__((ext_vector_type(8))) short bfvec8;
typedef __attribute__((ext_vector_type(4))) float fvec4;

__device__ __forceinline__ float bf2f(unsigned short u){
    union { unsigned int i; float f; } v; v.i = ((unsigned int)u) << 16; return v.f;
}
__device__ __forceinline__ unsigned short f2bf(float f){
    union { float f; unsigned int i; } v; v.f = f;
    unsigned int x = v.i;
    return (unsigned short)((x + 0x7fffu + ((x >> 16) & 1u)) >> 16);
}

__device__ __forceinline__ void gload_lds16(const void* g, void* lds){
    __builtin_amdgcn_global_load_lds(
        (const __attribute__((address_space(1))) void*)(uintptr_t)g,
        (__attribute__((address_space(3))) void*)(unsigned int)(uintptr_t)lds,
        16, 0, 0);
}

// ---- dequant 4-bit codes -> bf16 weights: w = (q/7.5 - 1) * scale[o][i/16]
__global__ __launch_bounds__(256) void prep_weights(const int* __restrict__ q,
                                                    const float* __restrict__ sc,
                                                    unsigned short* __restrict__ wbf){
    int idx = blockIdx.x * 256 + threadIdx.x;          // over 6*1024*1024
    int col  = idx & (Dm - 1);
    int rowl = idx >> 10;                               // l*1024 + o
    float s = sc[rowl * (Dm / 16) + (col >> 4)];
    float w = ((float)q[idx] * (1.0f / 7.5f) - 1.0f) * s;
    wbf[idx] = f2bf(w);
}

// ---- fp32 -> bf16 convert (n multiple of 1024)
__global__ __launch_bounds__(256) void conv_bf16_kernel(const float* __restrict__ in,
                                                        unsigned short* __restrict__ out){
    size_t i = ((size_t)blockIdx.x * 256 + threadIdx.x) * 4;
    float4 v = *(const float4*)(in + i);
    ushort4 o;
    o.x = f2bf(v.x); o.y = f2bf(v.y); o.z = f2bf(v.z); o.w = f2bf(v.w);
    *(ushort4*)(out + i) = o;
}

// ---- t = A[M,1024] @ la^T[1024,32] -> bf16 [M,32]; one block = 128 rows, wave = 32 rows
__global__ __launch_bounds__(256) void lora_t_kernel(const unsigned short* __restrict__ A,
                                                     const unsigned short* __restrict__ la,
                                                     unsigned short* __restrict__ T){
    const int wave = threadIdx.x >> 6, lane = threadIdx.x & 63;
    const int quad = lane >> 4, l16 = lane & 15;
    const int row_base = blockIdx.x * 128 + wave * 32;
    fvec4 acc[2][2] = {};
    for (int k = 0; k < Dm; k += 32) {
        bfvec8 a0 = *(const bfvec8*)(A + (size_t)(row_base + l16) * Dm + k + quad * 8);
        bfvec8 a1 = *(const bfvec8*)(A + (size_t)(row_base + 16 + l16) * Dm + k + quad * 8);
        bfvec8 b0 = *(const bfvec8*)(la + (size_t)(l16) * Dm + k + quad * 8);
        bfvec8 b1 = *(const bfvec8*)(la + (size_t)(16 + l16) * Dm + k + quad * 8);
        acc[0][0] = __builtin_amdgcn_mfma_f32_16x16x32_bf16(a0, b0, acc[0][0], 0, 0, 0);
        acc[0][1] = __builtin_amdgcn_mfma_f32_16x16x32_bf16(a0, b1, acc[0][1], 0, 0, 0);
        acc[1][0] = __builtin_amdgcn_mfma_f32_16x16x32_bf16(a1, b0, acc[1][0], 0, 0, 0);
        acc[1][1] = __builtin_amdgcn_mfma_f32_16x16x32_bf16(a1, b1, acc[1][1], 0, 0, 0);
    }
    #pragma unroll
    for (int mi = 0; mi < 2; mi++)
        #pragma unroll
        for (int ni = 0; ni < 2; ni++)
            #pragma unroll
            for (int r = 0; r < 4; r++) {
                int row = row_base + mi * 16 + quad * 4 + r;
                int col = ni * 16 + l16;
                T[(size_t)row * Rr + col] = f2bf(acc[mi][ni][r]);
            }
}

// ---- main GEMM: C[m,n] = sum_k A[m,k]*W[n,k] + sum_r T[m,r]*LB[n,r] + bias[n] (+resid)
// 128x128 tile, BK=64, 4 waves each 64x64 (4x4 of 16x16x32 bf16 MFMA).
// LDS XOR swizzle: granule kg (16B) of row R stored at slot kg ^ (R&7)  -> no bank conflicts.
// XCD supertile: bid%8 selects m-offset within a band of 8 m-tiles -> each XCD reuses one
// A-tile across all 8 n-tiles; W (2MB) stays L2-resident.
__global__ __launch_bounds__(256) void qlora_gemm(
    const unsigned short* __restrict__ A,
    const unsigned short* __restrict__ W,
    const unsigned short* __restrict__ T,
    const unsigned short* __restrict__ LB,
    const float* __restrict__ bias,
    const float* __restrict__ resid,
    float* __restrict__ outf,
    unsigned short* __restrict__ outb)
{
    __shared__ unsigned short As[128 * 64];
    __shared__ unsigned short Ws[128 * 64];
    const int tid = threadIdx.x;
    const int wave = tid >> 6, lane = tid & 63;
    const int quad = lane >> 4, l16 = lane & 15;
    const int wm = wave >> 1, wn = wave & 1;

    const int bid = blockIdx.x;                 // 2048 blocks
    const int within = bid & 63;                // 8m x 8n supertile band
    const int band = bid >> 6;
    const int m0 = (band * 8 + (within & 7)) * 128;
    const int n0 = (within >> 3) * 128;

    const int r8 = tid >> 3;                            // 0..31: row within pass
    const int o8 = (((tid & 7) ^ (r8 & 7)) * 8);        // swizzled source granule

    fvec4 acc[4][4] = {};

    for (int k0 = 0; k0 < Dm; k0 += 64) {
        #pragma unroll
        for (int p = 0; p < 4; p++) {
            int row = p * 32 + r8;
            gload_lds16(A + (size_t)(m0 + row) * Dm + k0 + o8,
                        (char*)As + (p * 256 + wave * 64) * 16);
            gload_lds16(W + (size_t)(n0 + row) * Dm + k0 + o8,
                        (char*)Ws + (p * 256 + wave * 64) * 16);
        }
        __syncthreads();
        #pragma unroll
        for (int ks = 0; ks < 64; ks += 32) {
            // slot for this (ks, quad) given R&7 == l16&7 (rows step by 16)
            const int s = (((ks >> 3) + quad) ^ (l16 & 7)) * 8;
            bfvec8 af[4], bw[4];
            #pragma unroll
            for (int i = 0; i < 4; i++) {
                af[i] = *(const bfvec8*)(As + (wm * 64 + i * 16 + l16) * 64 + s);
                bw[i] = *(const bfvec8*)(Ws + (wn * 64 + i * 16 + l16) * 64 + s);
            }
            #pragma unroll
            for (int mi = 0; mi < 4; mi++)
                #pragma unroll
                for (int ni = 0; ni < 4; ni++)
                    acc[mi][ni] = __builtin_amdgcn_mfma_f32_16x16x32_bf16(af[mi], bw[ni], acc[mi][ni], 0, 0, 0);
        }
        __syncthreads();
    }

    // LoRA tail: one K=32 step with T (A-operand) and LB (B-operand), direct global reads
    {
        bfvec8 tf[4], lf[4];
        #pragma unroll
        for (int i = 0; i < 4; i++) {
            tf[i] = *(const bfvec8*)(T + (size_t)(m0 + wm * 64 + i * 16 + l16) * Rr + quad * 8);
            lf[i] = *(const bfvec8*)(LB + (size_t)(n0 + wn * 64 + i * 16 + l16) * Rr + quad * 8);
        }
        #pragma unroll
        for (int mi = 0; mi < 4; mi++)
            #pragma unroll
            for (int ni = 0; ni < 4; ni++)
                acc[mi][ni] = __builtin_amdgcn_mfma_f32_16x16x32_bf16(tf[mi], lf[ni], acc[mi][ni], 0, 0, 0);
    }

    #pragma unroll
    for (int ni = 0; ni < 4; ni++) {
        const int col = n0 + wn * 64 + ni * 16 + l16;
        const float bv = bias[col];
        #pragma unroll
        for (int mi = 0; mi < 4; mi++) {
            const int rowb = m0 + wm * 64 + mi * 16 + quad * 4;
            #pragma unroll
            for (int r = 0; r < 4; r++) {
                float v = acc[mi][ni][r] + bv;
                size_t off = (size_t)(rowb + r) * Dm + col;
                if (resid) v += resid[off];
                if (outf) outf[off] = v;
                if (outb) outb[off] = f2bf(v);
            }
        }
    }
}

// ---- LayerNorm + exact GELU over rows of 1024, one block per row
__global__ __launch_bounds__(256) void ln_gelu_kernel(const unsigned short* __restrict__ Y,
                                                      const float* __restrict__ g,
                                                      const float* __restrict__ b,
                                                      unsigned short* __restrict__ Aout){
    const int row = blockIdx.x;
    const int tid = threadIdx.x;
    const unsigned short* yr = Y + (size_t)row * Dm;
    ushort4 u = *(const ushort4*)(yr + tid * 4);
    float x0 = bf2f(u.x), x1 = bf2f(u.y), x2 = bf2f(u.z), x3 = bf2f(u.w);
    float s  = x0 + x1 + x2 + x3;
    float ss = x0 * x0 + x1 * x1 + x2 * x2 + x3 * x3;
    #pragma unroll
    for (int d = 32; d > 0; d >>= 1) {
        s  += __shfl_down(s, d);
        ss += __shfl_down(ss, d);
    }
    __shared__ float sb[8];
    const int wave = tid >> 6, lane = tid & 63;
    if (lane == 0) { sb[wave] = s; sb[4 + wave] = ss; }
    __syncthreads();
    s  = sb[0] + sb[1] + sb[2] + sb[3];
    ss = sb[4] + sb[5] + sb[6] + sb[7];
    const float mu = s * (1.0f / Dm);
    const float var = ss * (1.0f / Dm) - mu * mu;
    const float rstd = rsqrtf(var + 1e-5f);
    float4 gv = *(const float4*)(g + tid * 4);
    float4 bv = *(const float4*)(b + tid * 4);
    float z0 = (x0 - mu) * rstd * gv.x + bv.x;
    float z1 = (x1 - mu) * rstd * gv.y + bv.y;
    float z2 = (x2 - mu) * rstd * gv.z + bv.z;
    float z3 = (x3 - mu) * rstd * gv.w + bv.w;
    const float k = 0.70710678118654752f;
    float a0 = 0.5f * z0 * (1.0f + erff(z0 * k));
    float a1 = 0.5f * z1 * (1.0f + erff(z1 * k));
    float a2 = 0.5f * z2 * (1.0f + erff(z2 * k));
    float a3 = 0.5f * z3 * (1.0f + erff(z3 * k));
    ushort4 o;
    o.x = f2bf(a0); o.y = f2bf(a1); o.z = f2bf(a2); o.w = f2bf(a3);
    *(ushort4*)(Aout + (size_t)row * Dm + tid * 4) = o;
}

extern "C" void kernel_launch(void* const* d_in, const int* in_sizes, int n_in,
                              void* d_out, int out_size, void* d_ws, size_t ws_size,
                              hipStream_t stream) {
    (void)in_sizes; (void)n_in; (void)out_size; (void)ws_size;
    const float* x   = (const float*)d_in[0];
    const int*   qw  = (const int*)d_in[1];
    const float* sc  = (const float*)d_in[2];
    const float* bia = (const float*)d_in[3];
    const float* la  = (const float*)d_in[4];
    const float* lb  = (const float*)d_in[5];
    const float* gam = (const float*)d_in[6];
    const float* bet = (const float*)d_in[7];
    float* out = (float*)d_out;

    char* p = (char*)d_ws;
    unsigned short* Wbf  = (unsigned short*)p; p += (size_t)NLAYER * Dm * Dm * 2;
    unsigned short* labf = (unsigned short*)p; p += (size_t)NLAYER * Rr * Dm * 2;
    unsigned short* lbbf = (unsigned short*)p; p += (size_t)NLAYER * Dm * Rr * 2;
    unsigned short* Tbuf = (unsigned short*)p; p += (size_t)MT * Rr * 2;
    unsigned short* Pb   = (unsigned short*)p; p += (size_t)MT * Dm * 2;
    unsigned short* Qb   = (unsigned short*)p; p += (size_t)MT * Dm * 2;

    prep_weights<<<NLAYER * Dm * Dm / 256, 256, 0, stream>>>(qw, sc, Wbf);
    conv_bf16_kernel<<<NLAYER * Rr * Dm / 4 / 256, 256, 0, stream>>>(la, labf);
    conv_bf16_kernel<<<NLAYER * Dm * Rr / 4 / 256, 256, 0, stream>>>(lb, lbbf);
    conv_bf16_kernel<<<MT * (Dm / 4) / 256, 256, 0, stream>>>(x, Pb);

    unsigned short *curP = Pb, *curQ = Qb;
    for (int blk = 0; blk < 3; blk++) {
        int i0 = 2 * blk, i1 = i0 + 1;
        lora_t_kernel<<<MT / 128, 256, 0, stream>>>(curP, labf + (size_t)i0 * Rr * Dm, Tbuf);
        qlora_gemm<<<2048, 256, 0, stream>>>(
            curP, Wbf + (size_t)i0 * Dm * Dm, Tbuf, lbbf + (size_t)i0 * Dm * Rr,
            bia + i0 * Dm, nullptr, nullptr, curQ);
        ln_gelu_kernel<<<MT, 256, 0, stream>>>(curQ, gam + blk * Dm, bet + blk * Dm, curP);
        lora_t_kernel<<<MT / 128, 256, 0, stream>>>(curP, labf + (size_t)i1 * Rr * Dm, Tbuf);
        qlora_gemm<<<2048, 256, 0, stream>>>(
            curP, Wbf + (size_t)i1 * Dm * Dm, Tbuf, lbbf + (size_t)i1 * Dm * Rr,
            bia + i1 * Dm, blk == 0 ? x : (const float*)out, out, curQ);
        unsigned short* t = curP; curP = curQ; curQ = t;
    }
}

// Round 3
// 1169.139 us; speedup vs baseline: 1.4500x; 1.3560x over previous
//
#include <hip/hip_runtime.h>
#include <hip/hip_bf16.h>
#include <stdint.h>

#define Dm 1024
#define Rr 32
#define MT 32768
#define NLAYER 6

typedef __attribute__((ext_vector_type(8))) short bfvec8;
typedef __attribute__((ext_vector_type(4))) float fvec4;

__device__ __forceinline__ float bf2f(unsigned short u){
    union { unsigned int i; float f; } v; v.i = ((unsigned int)u) << 16; return v.f;
}
__device__ __forceinline__ unsigned short f2bf(float f){
    union { float f; unsigned int i; } v; v.f = f;
    unsigned int x = v.i;
    return (unsigned short)((x + 0x7fffu + ((x >> 16) & 1u)) >> 16);
}

__device__ __forceinline__ void gload_lds16(const void* g, void* lds){
    __builtin_amdgcn_global_load_lds(
        (const __attribute__((address_space(1))) void*)(uintptr_t)g,
        (__attribute__((address_space(3))) void*)(unsigned int)(uintptr_t)lds,
        16, 0, 0);
}

// ---- dequant 4-bit codes -> bf16 weights: w = (q/7.5 - 1) * scale[o][i/16]
__global__ __launch_bounds__(256) void prep_weights(const int* __restrict__ q,
                                                    const float* __restrict__ sc,
                                                    unsigned short* __restrict__ wbf){
    int idx = blockIdx.x * 256 + threadIdx.x;          // over 6*1024*1024
    int col  = idx & (Dm - 1);
    int rowl = idx >> 10;                               // l*1024 + o
    float s = sc[rowl * (Dm / 16) + (col >> 4)];
    float w = ((float)q[idx] * (1.0f / 7.5f) - 1.0f) * s;
    wbf[idx] = f2bf(w);
}

// ---- fp32 -> bf16 convert (n multiple of 1024)
__global__ __launch_bounds__(256) void conv_bf16_kernel(const float* __restrict__ in,
                                                        unsigned short* __restrict__ out){
    size_t i = ((size_t)blockIdx.x * 256 + threadIdx.x) * 4;
    float4 v = *(const float4*)(in + i);
    ushort4 o;
    o.x = f2bf(v.x); o.y = f2bf(v.y); o.z = f2bf(v.z); o.w = f2bf(v.w);
    *(ushort4*)(out + i) = o;
}

// ---- t = A[M,1024] @ la^T[1024,32] -> bf16 [M,32]; one block = 128 rows, wave = 32 rows
__global__ __launch_bounds__(256) void lora_t_kernel(const unsigned short* __restrict__ A,
                                                     const unsigned short* __restrict__ la,
                                                     unsigned short* __restrict__ T){
    const int wave = threadIdx.x >> 6, lane = threadIdx.x & 63;
    const int quad = lane >> 4, l16 = lane & 15;
    const int row_base = blockIdx.x * 128 + wave * 32;
    fvec4 acc[2][2] = {};
    for (int k = 0; k < Dm; k += 32) {
        bfvec8 a0 = *(const bfvec8*)(A + (size_t)(row_base + l16) * Dm + k + quad * 8);
        bfvec8 a1 = *(const bfvec8*)(A + (size_t)(row_base + 16 + l16) * Dm + k + quad * 8);
        bfvec8 b0 = *(const bfvec8*)(la + (size_t)(l16) * Dm + k + quad * 8);
        bfvec8 b1 = *(const bfvec8*)(la + (size_t)(16 + l16) * Dm + k + quad * 8);
        acc[0][0] = __builtin_amdgcn_mfma_f32_16x16x32_bf16(a0, b0, acc[0][0], 0, 0, 0);
        acc[0][1] = __builtin_amdgcn_mfma_f32_16x16x32_bf16(a0, b1, acc[0][1], 0, 0, 0);
        acc[1][0] = __builtin_amdgcn_mfma_f32_16x16x32_bf16(a1, b0, acc[1][0], 0, 0, 0);
        acc[1][1] = __builtin_amdgcn_mfma_f32_16x16x32_bf16(a1, b1, acc[1][1], 0, 0, 0);
    }
    #pragma unroll
    for (int mi = 0; mi < 2; mi++)
        #pragma unroll
        for (int ni = 0; ni < 2; ni++)
            #pragma unroll
            for (int r = 0; r < 4; r++) {
                int row = row_base + mi * 16 + quad * 4 + r;
                int col = ni * 16 + l16;
                T[(size_t)row * Rr + col] = f2bf(acc[mi][ni][r]);
            }
}

// ---- main GEMM: C[m,n] = sum_k A[m,k]*W[n,k] + sum_r T[m,r]*LB[n,r] + bias[n] (+resid)
// 128x128 tile, BK=64, double-buffered LDS (2x32KB), ONE barrier per K-iter:
//   barrier (drains buf b's loads, issued last iter) -> prefetch buf b^1 -> compute buf b.
// LDS XOR swizzle keeps fragment reads conflict-free. Epilogue transposes C through LDS
// (reusing the 64KB staging buffer) for fully-coalesced float4 resid/out stores.
__global__ __launch_bounds__(256) void qlora_gemm(
    const unsigned short* __restrict__ A,
    const unsigned short* __restrict__ W,
    const unsigned short* __restrict__ T,
    const unsigned short* __restrict__ LB,
    const float* __restrict__ bias,
    const float* __restrict__ resid,
    float* __restrict__ outf,
    unsigned short* __restrict__ outb)
{
    __shared__ char smem[65536];
    unsigned short* As = (unsigned short*)smem;             // [2][128*64]
    unsigned short* Ws = (unsigned short*)(smem + 32768);   // [2][128*64]
    float* Cs = (float*)smem;                               // epilogue reuse [128][128]

    const int tid = threadIdx.x;
    const int wave = tid >> 6, lane = tid & 63;
    const int quad = lane >> 4, l16 = lane & 15;
    const int wm = wave >> 1, wn = wave & 1;

    const int bid = blockIdx.x;                 // 2048 blocks
    const int within = bid & 63;                // 8m x 8n supertile band
    const int band = bid >> 6;
    const int m0 = (band * 8 + (within & 7)) * 128;
    const int n0 = (within >> 3) * 128;

    const int r8 = tid >> 3;                            // 0..31: row within pass
    const int o8 = (((tid & 7) ^ (r8 & 7)) * 8);        // swizzled source granule

    fvec4 acc[4][4] = {};

    // stage one 128x64 A-tile + W-tile into buffer `buf`
    auto stage = [&](int buf, int k0) {
        #pragma unroll
        for (int p = 0; p < 4; p++) {
            int row = p * 32 + r8;
            gload_lds16(A + (size_t)(m0 + row) * Dm + k0 + o8,
                        (char*)As + buf * 16384 + (p * 256 + wave * 64) * 16);
            gload_lds16(W + (size_t)(n0 + row) * Dm + k0 + o8,
                        (char*)Ws + buf * 16384 + (p * 256 + wave * 64) * 16);
        }
    };

    stage(0, 0);
    #pragma unroll 2
    for (int k0 = 0; k0 < Dm; k0 += 64) {
        const int buf = (k0 >> 6) & 1;
        __syncthreads();                 // vmcnt(0) drain: buf's loads (issued last iter) done
        if (k0 + 64 < Dm) stage(buf ^ 1, k0 + 64);
        #pragma unroll
        for (int ks = 0; ks < 64; ks += 32) {
            // slot for this (ks, quad) given R&7 == l16&7 (rows step by 16)
            const int s = (((ks >> 3) + quad) ^ (l16 & 7)) * 8;
            bfvec8 af[4], bw[4];
            #pragma unroll
            for (int i = 0; i < 4; i++) {
                af[i] = *(const bfvec8*)(As + buf * 8192 + (wm * 64 + i * 16 + l16) * 64 + s);
                bw[i] = *(const bfvec8*)(Ws + buf * 8192 + (wn * 64 + i * 16 + l16) * 64 + s);
            }
            #pragma unroll
            for (int mi = 0; mi < 4; mi++)
                #pragma unroll
                for (int ni = 0; ni < 4; ni++)
                    acc[mi][ni] = __builtin_amdgcn_mfma_f32_16x16x32_bf16(af[mi], bw[ni], acc[mi][ni], 0, 0, 0);
        }
    }

    // LoRA tail: one K=32 step with T (A-operand) and LB (B-operand), direct global reads
    {
        bfvec8 tf[4], lf[4];
        #pragma unroll
        for (int i = 0; i < 4; i++) {
            tf[i] = *(const bfvec8*)(T + (size_t)(m0 + wm * 64 + i * 16 + l16) * Rr + quad * 8);
            lf[i] = *(const bfvec8*)(LB + (size_t)(n0 + wn * 64 + i * 16 + l16) * Rr + quad * 8);
        }
        #pragma unroll
        for (int mi = 0; mi < 4; mi++)
            #pragma unroll
            for (int ni = 0; ni < 4; ni++)
                acc[mi][ni] = __builtin_amdgcn_mfma_f32_16x16x32_bf16(tf[mi], lf[ni], acc[mi][ni], 0, 0, 0);
    }

    // ---- epilogue: acc -> LDS (row-major fp32) -> coalesced float4 out
    __syncthreads();                     // all LDS reads of As/Ws done; safe to reuse as Cs
    #pragma unroll
    for (int mi = 0; mi < 4; mi++)
        #pragma unroll
        for (int ni = 0; ni < 4; ni++)
            #pragma unroll
            for (int r = 0; r < 4; r++)
                Cs[(wm * 64 + mi * 16 + quad * 4 + r) * 128 + (wn * 64 + ni * 16 + l16)] = acc[mi][ni][r];
    __syncthreads();
    #pragma unroll
    for (int j = 0; j < 16; j++) {
        const int idx = j * 256 + tid;       // float4 index over 128x32
        const int row = idx >> 5;
        const int c4  = (idx & 31) * 4;
        float4 v = ((const float4*)Cs)[idx];
        float4 bv = *(const float4*)(bias + n0 + c4);
        v.x += bv.x; v.y += bv.y; v.z += bv.z; v.w += bv.w;
        const size_t off = (size_t)(m0 + row) * Dm + n0 + c4;
        if (resid) {
            float4 rv = *(const float4*)(resid + off);
            v.x += rv.x; v.y += rv.y; v.z += rv.z; v.w += rv.w;
        }
        if (outf) *(float4*)(outf + off) = v;
        if (outb) {
            ushort4 o;
            o.x = f2bf(v.x); o.y = f2bf(v.y); o.z = f2bf(v.z); o.w = f2bf(v.w);
            *(ushort4*)(outb + off) = o;
        }
    }
}

// ---- LayerNorm + exact GELU over rows of 1024, one block per row
__global__ __launch_bounds__(256) void ln_gelu_kernel(const unsigned short* __restrict__ Y,
                                                      const float* __restrict__ g,
                                                      const float* __restrict__ b,
                                                      unsigned short* __restrict__ Aout){
    const int row = blockIdx.x;
    const int tid = threadIdx.x;
    const unsigned short* yr = Y + (size_t)row * Dm;
    ushort4 u = *(const ushort4*)(yr + tid * 4);
    float x0 = bf2f(u.x), x1 = bf2f(u.y), x2 = bf2f(u.z), x3 = bf2f(u.w);
    float s  = x0 + x1 + x2 + x3;
    float ss = x0 * x0 + x1 * x1 + x2 * x2 + x3 * x3;
    #pragma unroll
    for (int d = 32; d > 0; d >>= 1) {
        s  += __shfl_down(s, d);
        ss += __shfl_down(ss, d);
    }
    __shared__ float sb[8];
    const int wave = tid >> 6, lane = tid & 63;
    if (lane == 0) { sb[wave] = s; sb[4 + wave] = ss; }
    __syncthreads();
    s  = sb[0] + sb[1] + sb[2] + sb[3];
    ss = sb[4] + sb[5] + sb[6] + sb[7];
    const float mu = s * (1.0f / Dm);
    const float var = ss * (1.0f / Dm) - mu * mu;
    const float rstd = rsqrtf(var + 1e-5f);
    float4 gv = *(const float4*)(g + tid * 4);
    float4 bv = *(const float4*)(b + tid * 4);
    float z0 = (x0 - mu) * rstd * gv.x + bv.x;
    float z1 = (x1 - mu) * rstd * gv.y + bv.y;
    float z2 = (x2 - mu) * rstd * gv.z + bv.z;
    float z3 = (x3 - mu) * rstd * gv.w + bv.w;
    const float k = 0.70710678118654752f;
    float a0 = 0.5f * z0 * (1.0f + erff(z0 * k));
    float a1 = 0.5f * z1 * (1.0f + erff(z1 * k));
    float a2 = 0.5f * z2 * (1.0f + erff(z2 * k));
    float a3 = 0.5f * z3 * (1.0f + erff(z3 * k));
    ushort4 o;
    o.x = f2bf(a0); o.y = f2bf(a1); o.z = f2bf(a2); o.w = f2bf(a3);
    *(ushort4*)(Aout + (size_t)row * Dm + tid * 4) = o;
}

extern "C" void kernel_launch(void* const* d_in, const int* in_sizes, int n_in,
                              void* d_out, int out_size, void* d_ws, size_t ws_size,
                              hipStream_t stream) {
    (void)in_sizes; (void)n_in; (void)out_size; (void)ws_size;
    const float* x   = (const float*)d_in[0];
    const int*   qw  = (const int*)d_in[1];
    const float* sc  = (const float*)d_in[2];
    const float* bia = (const float*)d_in[3];
    const float* la  = (const float*)d_in[4];
    const float* lb  = (const float*)d_in[5];
    const float* gam = (const float*)d_in[6];
    const float* bet = (const float*)d_in[7];
    float* out = (float*)d_out;

    char* p = (char*)d_ws;
    unsigned short* Wbf  = (unsigned short*)p; p += (size_t)NLAYER * Dm * Dm * 2;
    unsigned short* labf = (unsigned short*)p; p += (size_t)NLAYER * Rr * Dm * 2;
    unsigned short* lbbf = (unsigned short*)p; p += (size_t)NLAYER * Dm * Rr * 2;
    unsigned short* Tbuf = (unsigned short*)p; p += (size_t)MT * Rr * 2;
    unsigned short* Pb   = (unsigned short*)p; p += (size_t)MT * Dm * 2;
    unsigned short* Qb   = (unsigned short*)p; p += (size_t)MT * Dm * 2;

    prep_weights<<<NLAYER * Dm * Dm / 256, 256, 0, stream>>>(qw, sc, Wbf);
    conv_bf16_kernel<<<NLAYER * Rr * Dm / 4 / 256, 256, 0, stream>>>(la, labf);
    conv_bf16_kernel<<<NLAYER * Dm * Rr / 4 / 256, 256, 0, stream>>>(lb, lbbf);
    conv_bf16_kernel<<<MT * (Dm / 4) / 256, 256, 0, stream>>>(x, Pb);

    unsigned short *curP = Pb, *curQ = Qb;
    for (int blk = 0; blk < 3; blk++) {
        int i0 = 2 * blk, i1 = i0 + 1;
        lora_t_kernel<<<MT / 128, 256, 0, stream>>>(curP, labf + (size_t)i0 * Rr * Dm, Tbuf);
        qlora_gemm<<<2048, 256, 0, stream>>>(
            curP, Wbf + (size_t)i0 * Dm * Dm, Tbuf, lbbf + (size_t)i0 * Dm * Rr,
            bia + i0 * Dm, nullptr, nullptr, curQ);
        ln_gelu_kernel<<<MT, 256, 0, stream>>>(curQ, gam + blk * Dm, bet + blk * Dm, curP);
        lora_t_kernel<<<MT / 128, 256, 0, stream>>>(curP, labf + (size_t)i1 * Rr * Dm, Tbuf);
        qlora_gemm<<<2048, 256, 0, stream>>>(
            curP, Wbf + (size_t)i1 * Dm * Dm, Tbuf, lbbf + (size_t)i1 * Dm * Rr,
            bia + i1 * Dm, blk == 0 ? x : (const float*)out, out, curQ);
        unsigned short* t = curP; curP = curQ; curQ = t;
    }
}